// Round 7
// baseline (321.043 us; speedup 1.0000x reference)
//
#include <hip/hip_runtime.h>

#define Bb 2
#define Cc 64
#define Hh 48
#define Ww 48
#define Ll 48
#define HWc (Hh*Ww)          /* 2304 */
#define HWL (HWc*Ll)         /* 110592 */
#define GHh 24
#define SG (GHh*GHh*GHh)     /* 13824 */
#define NBLK (Bb*HWc)        /* 4608 */
#define CNT1f 110592.0f
#define CNT2f 9437184.0f     /* HW*C*C */

// half-pixel trilinear taps for 24 -> 48 (matches jax.image.resize 'trilinear')
__device__ __forceinline__ void interp1(int i, int& a, int& b, float& f){
  float src = i*0.5f - 0.25f;
  float fl = floorf(src);
  f = src - fl;
  int i0 = (int)fl;
  a = i0 < 0 ? 0 : i0;
  int i1 = i0 + 1;
  b = i1 > (GHh-1) ? (GHh-1) : i1;
}

// integer form of the l-taps (bit-identical: fl is exactly 0.25/0.75)
__device__ __forceinline__ void ltaps(int l, int& a, int& b, float& f){
  int i0 = (l - 1) >> 1;             // arithmetic shift; l=0 -> -1
  a = i0 < 0 ? 0 : i0;
  b = i0 + 1 > 23 ? 23 : i0 + 1;
  f = (l & 1) ? 0.25f : 0.75f;
}

// out[b,o,s] = sum_c W[o,c]*in[b,c,s] + bias[o]
__global__ __launch_bounds__(256) void conv_k(const float* __restrict__ in,
    const float* __restrict__ Wm, const float* __restrict__ bias,
    float* __restrict__ out, int S){
  __shared__ __align__(16) float Wl[64][68];   // Wl[c][o]
  __shared__ __align__(16) float xl[64][68];   // xl[c][s]
  int t = threadIdx.x;
  int ntile = S >> 6;
  int b  = blockIdx.x / ntile;
  int s0 = (blockIdx.x % ntile) << 6;
  for (int q = t; q < 4096; q += 256){
    int o = q >> 6, c = q & 63;
    Wl[c][o] = Wm[q];
  }
  const float* inb = in + (size_t)b*Cc*S + s0;
  for (int q = t; q < 1024; q += 256){
    int c = q >> 4, v = (q & 15) << 2;
    float4 val = *(const float4*)(inb + (size_t)c*S + v);
    *(float4*)&xl[c][v] = val;
  }
  __syncthreads();
  int o0 = (t & 15) << 2, s1 = (t >> 4) << 2;
  float a00=0,a01=0,a02=0,a03=0,a10=0,a11=0,a12=0,a13=0;
  float a20=0,a21=0,a22=0,a23=0,a30=0,a31=0,a32=0,a33=0;
  #pragma unroll 8
  for (int c = 0; c < 64; ++c){
    float4 wv = *(const float4*)&Wl[c][o0];
    float4 xv = *(const float4*)&xl[c][s1];
    a00 += wv.x*xv.x; a01 += wv.x*xv.y; a02 += wv.x*xv.z; a03 += wv.x*xv.w;
    a10 += wv.y*xv.x; a11 += wv.y*xv.y; a12 += wv.y*xv.z; a13 += wv.y*xv.w;
    a20 += wv.z*xv.x; a21 += wv.z*xv.y; a22 += wv.z*xv.z; a23 += wv.z*xv.w;
    a30 += wv.w*xv.x; a31 += wv.w*xv.y; a32 += wv.w*xv.z; a33 += wv.w*xv.w;
  }
  float* ob = out + (size_t)b*Cc*S + s0 + s1;
  float b0 = bias[o0+0], b1v = bias[o0+1], b2v = bias[o0+2], b3 = bias[o0+3];
  { float4 r = make_float4(a00+b0,a01+b0,a02+b0,a03+b0); *(float4*)(ob + (size_t)(o0+0)*S) = r; }
  { float4 r = make_float4(a10+b1v,a11+b1v,a12+b1v,a13+b1v); *(float4*)(ob + (size_t)(o0+1)*S) = r; }
  { float4 r = make_float4(a20+b2v,a21+b2v,a22+b2v,a23+b2v); *(float4*)(ob + (size_t)(o0+2)*S) = r; }
  { float4 r = make_float4(a30+b3,a31+b3,a32+b3,a33+b3); *(float4*)(ob + (size_t)(o0+3)*S) = r; }
}

// G-fold: G[k][c] = sum_l w(l,k)*txt[c][l] (txt stride 52) — transposed
// 48->24 interp weights.
__device__ __forceinline__ void g_fold(const float* __restrict__ txt,
    float* __restrict__ G, int t){
  int c = t >> 2, kb = (t & 3)*6;
  const float* T = &txt[c*52];
  #pragma unroll
  for (int i = 0; i < 6; ++i){
    int k = kb + i;
    float v;
    if (k == 0)       v = T[0] + 0.75f*T[1] + 0.25f*T[2];
    else if (k == 23) v = 0.25f*T[45] + 0.75f*T[46] + T[47];
    else              v = 0.25f*T[2*k-1] + 0.75f*T[2*k]
                        + 0.75f*T[2*k+1] + 0.25f*T[2*k+2];
    G[k*68 + c] = v;
  }
}

// M[k][c] = bilinear(h,w) of half-res tgh (h-lerp then w-lerp).
__device__ __forceinline__ void gather_m(const float* __restrict__ gb,
    float* __restrict__ M, int t, int ha, int hb, int wa, int wb,
    float fh, float fw){
  float omh = 1.f - fh, omw = 1.f - fw;
  for (int u = t; u < 384; u += 256){
    int c = u / 6, s4 = (u % 6) << 2;
    const float* gc = gb + (size_t)c*SG;
    float4 vaa = *(const float4*)(gc + ha*576 + wa*24 + s4);
    float4 vba = *(const float4*)(gc + hb*576 + wa*24 + s4);
    float4 vab = *(const float4*)(gc + ha*576 + wb*24 + s4);
    float4 vbb = *(const float4*)(gc + hb*576 + wb*24 + s4);
    M[(s4+0)*68 + c] = omw*(omh*vaa.x + fh*vba.x) + fw*(omh*vab.x + fh*vbb.x);
    M[(s4+1)*68 + c] = omw*(omh*vaa.y + fh*vba.y) + fw*(omh*vab.y + fh*vbb.y);
    M[(s4+2)*68 + c] = omw*(omh*vaa.z + fh*vba.z) + fw*(omh*vab.z + fh*vbb.z);
    M[(s4+3)*68 + c] = omw*(omh*vaa.w + fh*vba.w) + fw*(omh*vab.w + fh*vbb.w);
  }
}

// one block per (b,h,w) site: partials + msite + gsite stores.
__global__ __launch_bounds__(256) void reduce_k(const float* __restrict__ tx,
    const float* __restrict__ tgh, float* __restrict__ msite,
    float* __restrict__ gsite, float* __restrict__ part_row,
    float* __restrict__ pm1, float* __restrict__ pm2, float* __restrict__ ps2){
  __shared__ __align__(16) float sh[7224];
  float* txt = sh;            // [64][52]
  float* M   = sh + 3328;     // [24][68]  k-major
  float* G   = sh + 4960;     // [24][68]  k-major
  float* red = sh + 6592;     // [512]
  float* CM  = sh + 7104;     // [24]
  float* SX  = sh + 7128;     // [48]
  float* sxg = sh + 7176;     // [48]
  int t = threadIdx.x;
  int bIdx = blockIdx.x;
  int b = bIdx / HWc, hw = bIdx % HWc;
  int h = hw / Ww, w = hw % Ww;
  int ha, hb; float fh; interp1(h, ha, hb, fh);
  int wa, wb; float fw; interp1(w, wa, wb, fw);
  const float* txb = tx + ((size_t)b*Cc*HWc + hw)*Ll;
  #pragma unroll
  for (int k = 0; k < 3; ++k){
    int q = t + (k << 8);
    int c = q / 12, v = (q % 12) << 2;
    *(float4*)&txt[c*52+v] = *(const float4*)(txb + (size_t)c*HWL + v);
  }
  gather_m(tgh + (size_t)b*Cc*SG, M, t, ha, hb, wa, wb, fh, fw);
  __syncthreads();
  g_fold(txt, G, t);
  if (t < 24){
    float s = 0.f;
    #pragma unroll 8
    for (int c = 0; c < 64; ++c) s += M[t*68 + c];
    CM[t] = s;
  }
  if (t >= 192 && t < 240){
    int l = t - 192;
    float s = 0.f;
    #pragma unroll 8
    for (int c = 0; c < 64; ++c) s += txt[c*52 + l];
    SX[l] = s;
  }
  __syncthreads();
  // elementwise product min; l-partition rotated by c (bank spread), int taps
  int c = t & 63, lg = t >> 6;
  float pmin = 3.4e38f;
  const float* Trow = &txt[c*52];
  #pragma unroll
  for (int li = 0; li < 12; ++li){
    int l0r = lg*12 + li + c;
    int l = l0r >= 96 ? l0r - 96 : (l0r >= 48 ? l0r - 48 : l0r);
    int la, lb; float fl; ltaps(l, la, lb, fl);
    float tgv = (1.f-fl)*M[la*68 + c] + fl*M[lb*68 + c];
    pmin = fminf(pmin, Trow[l]*tgv);
  }
  if (t < 48){
    int la, lb; float fl; ltaps(t, la, lb, fl);
    sxg[t] = SX[t] * ((1.f-fl)*CM[la] + fl*CM[lb]);
  }
  // store M and G site-major for final_k (contiguous, coalesced)
  float* msb = msite + (size_t)bIdx*1536;
  float* gsb = gsite + (size_t)bIdx*1536;
  for (int u = t; u < 384; u += 256){
    int k = u >> 4, c4 = (u & 15) << 2;
    float4 mv;
    mv.x = M[k*68+c4+0]; mv.y = M[k*68+c4+1];
    mv.z = M[k*68+c4+2]; mv.w = M[k*68+c4+3];
    *(float4*)(msb + (u << 2)) = mv;
    float4 gv;
    gv.x = G[k*68+c4+0]; gv.y = G[k*68+c4+1];
    gv.z = G[k*68+c4+2]; gv.w = G[k*68+c4+3];
    *(float4*)(gsb + (u << 2)) = gv;
  }
  // At[i][j] = sum_k G[k][i]*M[k][j]; amin + diag (=rowsum partial)
  int i0 = (t & 15) << 2, j0 = (t >> 4) << 2;
  float a00=0,a01=0,a02=0,a03=0,a10=0,a11=0,a12=0,a13=0;
  float a20=0,a21=0,a22=0,a23=0,a30=0,a31=0,a32=0,a33=0;
  #pragma unroll 4
  for (int k = 0; k < 24; ++k){
    float4 gv = *(const float4*)&G[k*68 + i0];
    float4 mv = *(const float4*)&M[k*68 + j0];
    a00 += gv.x*mv.x; a01 += gv.x*mv.y; a02 += gv.x*mv.z; a03 += gv.x*mv.w;
    a10 += gv.y*mv.x; a11 += gv.y*mv.y; a12 += gv.y*mv.z; a13 += gv.y*mv.w;
    a20 += gv.z*mv.x; a21 += gv.z*mv.y; a22 += gv.z*mv.z; a23 += gv.z*mv.w;
    a30 += gv.w*mv.x; a31 += gv.w*mv.y; a32 += gv.w*mv.z; a33 += gv.w*mv.w;
  }
  float amin = fminf(fminf(fminf(a00,a01),fminf(a02,a03)),
               fminf(fminf(fminf(a10,a11),fminf(a12,a13)),
               fminf(fminf(fminf(a20,a21),fminf(a22,a23)),
                     fminf(fminf(a30,a31),fminf(a32,a33)))));
  if ((t & 15) == (t >> 4)){
    float* pr = part_row + (size_t)bIdx*64 + i0;
    pr[0] = a00; pr[1] = a11; pr[2] = a22; pr[3] = a33;
  }
  red[t] = pmin; red[256+t] = amin;
  __syncthreads();
  if (t < 128){
    red[t] = fminf(red[t], red[t+128]);
    red[256+t] = fminf(red[256+t], red[384+t]);
  }
  __syncthreads();
  if (t < 64){
    float v1 = fminf(red[t], red[t+64]);
    float v2 = fminf(red[256+t], red[320+t]);
    #pragma unroll
    for (int off = 32; off; off >>= 1){
      v1 = fminf(v1, __shfl_down(v1, off));
      v2 = fminf(v2, __shfl_down(v2, off));
    }
    if (t == 0){
      pm1[bIdx] = v1; pm2[bIdx] = v2;
      float tot = 0.f;
      #pragma unroll
      for (int l = 0; l < 48; ++l) tot += sxg[l];
      ps2[bIdx] = tot;
    }
  }
}

// parallel second-stage reduction: 130 blocks (unchanged)
__global__ __launch_bounds__(256) void reduce2_k(const float* __restrict__ part_row,
    const float* __restrict__ pm1, const float* __restrict__ pm2,
    const float* __restrict__ ps2, float* __restrict__ rowsum,
    float* __restrict__ gmin, float* __restrict__ s2v){
  __shared__ float red[512];
  int t = threadIdx.x, blk = blockIdx.x;
  if (blk < 128){
    int b = blk >> 6, c = blk & 63;
    const float* src = part_row + (size_t)b*HWc*64 + c;
    float s = 0.f;
    #pragma unroll
    for (int k = 0; k < 9; ++k){
      int i = t + (k << 8);
      s += src[(size_t)i*64];
    }
    red[t] = s; __syncthreads();
    for (int sgap = 128; sgap >= 64; sgap >>= 1){
      if (t < sgap) red[t] += red[t+sgap];
      __syncthreads();
    }
    if (t < 64){
      float v = red[t];
      #pragma unroll
      for (int off = 32; off; off >>= 1) v += __shfl_down(v, off);
      if (t == 0) rowsum[blk] = v;
    }
  } else if (blk == 128){
    float m1 = 3.4e38f, m2 = 3.4e38f;
    for (int i = t; i < NBLK; i += 256){ m1 = fminf(m1, pm1[i]); m2 = fminf(m2, pm2[i]); }
    red[t] = m1; red[256+t] = m2; __syncthreads();
    for (int s = 128; s >= 1; s >>= 1){
      if (t < s){ red[t] = fminf(red[t], red[t+s]); red[256+t] = fminf(red[256+t], red[256+t+s]); }
      __syncthreads();
    }
    if (t == 0){ gmin[0] = red[0]; gmin[1] = red[256]; }
  } else {
    float sa = 0.f, sb = 0.f;
    for (int i = t; i < HWc; i += 256){ sa += ps2[i]; sb += ps2[HWc + i]; }
    red[t] = sa; red[256+t] = sb; __syncthreads();
    for (int s = 128; s >= 1; s >>= 1){
      if (t < s){ red[t] += red[t+s]; red[256+t] += red[256+t+s]; }
      __syncthreads();
    }
    if (t == 0){ s2v[0] = red[0]; s2v[1] = red[256]; }
  }
}

// one block per (b,h,w): p (tx streamed from global) and d (via P = G·x,
// never forming At). LDS 31808 B -> 5 blocks/CU.
__global__ __launch_bounds__(256) void final_k(const float* __restrict__ x,
    const float* __restrict__ tx, const float* __restrict__ msite,
    const float* __restrict__ gsite, const float* __restrict__ gmin,
    const float* __restrict__ rowsum, const float* __restrict__ s2v,
    float* __restrict__ outp, float* __restrict__ outd){
  __shared__ __align__(16) float sh[7952];
  float* xs  = sh;            // [64][52] 3328
  float* M   = sh + 3328;     // [24][68] 1632
  float* G   = sh + 4960;     // [24][68] 1632
  float* P   = sh + 6592;     // [24][52] 1248
  float* iv1 = sh + 7840;     // [64]
  float* Xs  = sh + 7904;     // [48]
  int t = threadIdx.x;
  int bIdx = blockIdx.x;
  int b = bIdx / HWc, hw = bIdx % HWc;
  size_t sbase = ((size_t)b*Cc*HWc + hw)*Ll;
  const float* xb  = x  + sbase;
  const float* txb = tx + sbase;
  float m1 = gmin[0], m2 = gmin[1];
  #pragma unroll
  for (int k = 0; k < 3; ++k){
    int q = t + (k << 8);
    int c = q / 12, v = (q % 12) << 2;
    *(float4*)&xs[c*52+v] = *(const float4*)(xb + (size_t)c*HWL + v);
  }
  const float* msb = msite + (size_t)bIdx*1536;
  const float* gsb = gsite + (size_t)bIdx*1536;
  for (int u = t; u < 384; u += 256){
    int k = u >> 4, c4 = (u & 15) << 2;
    *(float4*)&M[k*68 + c4] = *(const float4*)(msb + (u << 2));
    *(float4*)&G[k*68 + c4] = *(const float4*)(gsb + (u << 2));
  }
  if (t < 64) iv1[t] = 1.f/(rowsum[b*64 + t] - m1*CNT1f);
  float invd2 = 1.f/(s2v[b] - m2*CNT2f);
  __syncthreads();
  // P[k][l] = sum_c G[k][c]*x[c][l]  (192 thr: 1k x 6l each)
  if (t < 192){
    int k0 = t >> 3, l0 = (t & 7)*6;
    float c0=0,c1=0,c2=0,c3=0,c4=0,c5=0;
    const float* Gr = &G[k0*68];
    #pragma unroll 8
    for (int i = 0; i < 64; ++i){
      float gv = Gr[i];
      const float* xr = &xs[i*52 + l0];
      c0 += gv*xr[0]; c1 += gv*xr[1]; c2 += gv*xr[2];
      c3 += gv*xr[3]; c4 += gv*xr[4]; c5 += gv*xr[5];
    }
    float* pr = &P[k0*52 + l0];
    pr[0]=c0; pr[1]=c1; pr[2]=c2; pr[3]=c3; pr[4]=c4; pr[5]=c5;
  } else if (t < 240){
    int l = t - 192;
    float s = 0.f;
    #pragma unroll 8
    for (int c = 0; c < 64; ++c) s += xs[c*52 + l];
    Xs[l] = s;
  }
  // p = (tx*tg - m1)*iv1[c]*x  — tx streamed, tg expanded via shared taps
  // (taps for quad l4..l4+3, h=l4>>1: Mm1=M[max(h-1,0)], M0=M[h], M1=M[h+1],
  //  M2=M[min(h+2,23)]; lerps bit-identical to interp1 form)
  __syncthreads();
  #pragma unroll
  for (int k = 0; k < 3; ++k){
    int q = t + (k << 8);
    int c = q / 12, l4 = (q % 12) << 2;
    int hh = l4 >> 1;
    int im1 = hh - 1 < 0 ? 0 : hh - 1;
    int ip2 = hh + 2 > 23 ? 23 : hh + 2;
    float Mm1 = M[im1*68 + c];
    float M0  = M[hh*68 + c];
    float M1  = M[(hh+1)*68 + c];
    float M2  = M[ip2*68 + c];
    float4 a  = *(const float4*)(txb + (size_t)c*HWL + l4);
    float4 xv = *(const float4*)&xs[c*52 + l4];
    float s = iv1[c];
    float4 r;
    r.x = (a.x*(0.25f*Mm1 + 0.75f*M0) - m1)*s*xv.x;
    r.y = (a.y*(0.75f*M0  + 0.25f*M1) - m1)*s*xv.y;
    r.z = (a.z*(0.25f*M0  + 0.75f*M1) - m1)*s*xv.z;
    r.w = (a.w*(0.75f*M1  + 0.25f*M2) - m1)*s*xv.w;
    *(float4*)(outp + sbase + (size_t)c*HWL + l4) = r;
  }
  __syncthreads();   // P/Xs ready
  // d[j][l] = invd2*(sum_k M[k][j]*P[k][l] - m2*Xs[l]); 256 thr: 4j x 3l
  {
    int j0 = (t >> 4) << 2, l0 = (t & 15)*3;
    float d00=0,d01=0,d02=0,d10=0,d11=0,d12=0;
    float d20=0,d21=0,d22=0,d30=0,d31=0,d32=0;
    #pragma unroll 4
    for (int k = 0; k < 24; ++k){
      float4 mv = *(const float4*)&M[k*68 + j0];
      const float* pr = &P[k*52 + l0];
      float p0 = pr[0], p1 = pr[1], p2 = pr[2];
      d00 += mv.x*p0; d01 += mv.x*p1; d02 += mv.x*p2;
      d10 += mv.y*p0; d11 += mv.y*p1; d12 += mv.y*p2;
      d20 += mv.z*p0; d21 += mv.z*p1; d22 += mv.z*p2;
      d30 += mv.w*p0; d31 += mv.w*p1; d32 += mv.w*p2;
    }
    float x0 = m2*Xs[l0+0], x1 = m2*Xs[l0+1], x2 = m2*Xs[l0+2];
    float* o0 = outd + sbase + (size_t)(j0+0)*HWL + l0;
    float* o1 = outd + sbase + (size_t)(j0+1)*HWL + l0;
    float* o2 = outd + sbase + (size_t)(j0+2)*HWL + l0;
    float* o3 = outd + sbase + (size_t)(j0+3)*HWL + l0;
    o0[0]=(d00-x0)*invd2; o0[1]=(d01-x1)*invd2; o0[2]=(d02-x2)*invd2;
    o1[0]=(d10-x0)*invd2; o1[1]=(d11-x1)*invd2; o1[2]=(d12-x2)*invd2;
    o2[0]=(d20-x0)*invd2; o2[1]=(d21-x1)*invd2; o2[2]=(d22-x2)*invd2;
    o3[0]=(d30-x0)*invd2; o3[1]=(d31-x1)*invd2; o3[2]=(d32-x2)*invd2;
  }
}

extern "C" void kernel_launch(void* const* d_in, const int* in_sizes, int n_in,
                              void* d_out, int out_size, void* d_ws, size_t ws_size,
                              hipStream_t stream){
  (void)in_sizes; (void)n_in; (void)out_size; (void)ws_size;
  const float* x  = (const float*)d_in[0];
  const float* g  = (const float*)d_in[1];
  const float* W1 = (const float*)d_in[2];
  const float* b1 = (const float*)d_in[3];
  const float* W2 = (const float*)d_in[4];
  const float* b2 = (const float*)d_in[5];
  float* outp = (float*)d_out;
  float* outd = outp + (size_t)Bb*Cc*HWL;
  float* ws   = (float*)d_ws;
  float* txw    = ws;                               // 14,155,776 floats
  float* tghw   = txw + (size_t)Bb*Cc*HWL;          // 1,769,472
  float* msite  = tghw + (size_t)Bb*Cc*SG;          // NBLK*1536
  float* gsite  = msite + (size_t)NBLK*1536;        // NBLK*1536
  float* part_row = gsite + (size_t)NBLK*1536;      // NBLK*64
  float* pm1 = part_row + (size_t)NBLK*64;          // NBLK
  float* pm2 = pm1 + NBLK;                          // NBLK
  float* ps2 = pm2 + NBLK;                          // NBLK
  float* rowsum = ps2 + NBLK;                       // 128
  float* gmin = rowsum + 128;                       // 2
  float* s2v  = gmin + 2;                           // 2

  hipLaunchKernelGGL(conv_k, dim3(Bb*(SG/64)), dim3(256), 0, stream, g, W2, b2, tghw, SG);
  hipLaunchKernelGGL(conv_k, dim3(Bb*(HWL/64)), dim3(256), 0, stream, x, W1, b1, txw, HWL);
  hipLaunchKernelGGL(reduce_k, dim3(NBLK), dim3(256), 0, stream, txw, tghw, msite, gsite,
                     part_row, pm1, pm2, ps2);
  hipLaunchKernelGGL(reduce2_k, dim3(130), dim3(256), 0, stream, part_row, pm1, pm2, ps2,
                     rowsum, gmin, s2v);
  hipLaunchKernelGGL(final_k, dim3(NBLK), dim3(256), 0, stream, x, txw, msite, gsite,
                     gmin, rowsum, s2v, outp, outd);
}

// Round 8
// 318.580 us; speedup vs baseline: 1.0077x; 1.0077x over previous
//
#include <hip/hip_runtime.h>

#define Bb 2
#define Cc 64
#define Hh 48
#define Ww 48
#define Ll 48
#define HWc (Hh*Ww)          /* 2304 */
#define HWL (HWc*Ll)         /* 110592 */
#define GHh 24
#define SG (GHh*GHh*GHh)     /* 13824 */
#define NBLK (Bb*HWc)        /* 4608 */
#define CNT1f 110592.0f
#define CNT2f 9437184.0f     /* HW*C*C */

// half-pixel trilinear taps for 24 -> 48 (matches jax.image.resize 'trilinear')
__device__ __forceinline__ void interp1(int i, int& a, int& b, float& f){
  float src = i*0.5f - 0.25f;
  float fl = floorf(src);
  f = src - fl;
  int i0 = (int)fl;
  a = i0 < 0 ? 0 : i0;
  int i1 = i0 + 1;
  b = i1 > (GHh-1) ? (GHh-1) : i1;
}

// integer form of the l-taps (bit-identical: fl is exactly 0.25/0.75)
__device__ __forceinline__ void ltaps(int l, int& a, int& b, float& f){
  int i0 = (l - 1) >> 1;             // arithmetic shift; l=0 -> -1
  a = i0 < 0 ? 0 : i0;
  b = i0 + 1 > 23 ? 23 : i0 + 1;
  f = (l & 1) ? 0.25f : 0.75f;
}

// out[b,o,s] = sum_c W[o,c]*in[b,c,s] + bias[o] — used only for theta_g (half-res)
__global__ __launch_bounds__(256) void conv_k(const float* __restrict__ in,
    const float* __restrict__ Wm, const float* __restrict__ bias,
    float* __restrict__ out, int S){
  __shared__ __align__(16) float Wl[64][68];   // Wl[c][o]
  __shared__ __align__(16) float xl[64][68];   // xl[c][s]
  int t = threadIdx.x;
  int ntile = S >> 6;
  int b  = blockIdx.x / ntile;
  int s0 = (blockIdx.x % ntile) << 6;
  for (int q = t; q < 4096; q += 256){
    int o = q >> 6, c = q & 63;
    Wl[c][o] = Wm[q];
  }
  const float* inb = in + (size_t)b*Cc*S + s0;
  for (int q = t; q < 1024; q += 256){
    int c = q >> 4, v = (q & 15) << 2;
    float4 val = *(const float4*)(inb + (size_t)c*S + v);
    *(float4*)&xl[c][v] = val;
  }
  __syncthreads();
  int o0 = (t & 15) << 2, s1 = (t >> 4) << 2;
  float a00=0,a01=0,a02=0,a03=0,a10=0,a11=0,a12=0,a13=0;
  float a20=0,a21=0,a22=0,a23=0,a30=0,a31=0,a32=0,a33=0;
  #pragma unroll 8
  for (int c = 0; c < 64; ++c){
    float4 wv = *(const float4*)&Wl[c][o0];
    float4 xv = *(const float4*)&xl[c][s1];
    a00 += wv.x*xv.x; a01 += wv.x*xv.y; a02 += wv.x*xv.z; a03 += wv.x*xv.w;
    a10 += wv.y*xv.x; a11 += wv.y*xv.y; a12 += wv.y*xv.z; a13 += wv.y*xv.w;
    a20 += wv.z*xv.x; a21 += wv.z*xv.y; a22 += wv.z*xv.z; a23 += wv.z*xv.w;
    a30 += wv.w*xv.x; a31 += wv.w*xv.y; a32 += wv.w*xv.z; a33 += wv.w*xv.w;
  }
  float* ob = out + (size_t)b*Cc*S + s0 + s1;
  float b0 = bias[o0+0], b1v = bias[o0+1], b2v = bias[o0+2], b3 = bias[o0+3];
  { float4 r = make_float4(a00+b0,a01+b0,a02+b0,a03+b0); *(float4*)(ob + (size_t)(o0+0)*S) = r; }
  { float4 r = make_float4(a10+b1v,a11+b1v,a12+b1v,a13+b1v); *(float4*)(ob + (size_t)(o0+1)*S) = r; }
  { float4 r = make_float4(a20+b2v,a21+b2v,a22+b2v,a23+b2v); *(float4*)(ob + (size_t)(o0+2)*S) = r; }
  { float4 r = make_float4(a30+b3,a31+b3,a32+b3,a33+b3); *(float4*)(ob + (size_t)(o0+3)*S) = r; }
}

// G-fold: G[k][c] = sum_l w(l,k)*txt[c][l] (txt stride 52)
__device__ __forceinline__ void g_fold(const float* __restrict__ txt,
    float* __restrict__ G, int t){
  int c = t >> 2, kb = (t & 3)*6;
  const float* T = &txt[c*52];
  #pragma unroll
  for (int i = 0; i < 6; ++i){
    int k = kb + i;
    float v;
    if (k == 0)       v = T[0] + 0.75f*T[1] + 0.25f*T[2];
    else if (k == 23) v = 0.25f*T[45] + 0.75f*T[46] + T[47];
    else              v = 0.25f*T[2*k-1] + 0.75f*T[2*k]
                        + 0.75f*T[2*k+1] + 0.25f*T[2*k+2];
    G[k*68 + c] = v;
  }
}

// M[k][c] = bilinear(h,w) of half-res tgh (h-lerp then w-lerp).
__device__ __forceinline__ void gather_m(const float* __restrict__ gb,
    float* __restrict__ M, int t, int ha, int hb, int wa, int wb,
    float fh, float fw){
  float omh = 1.f - fh, omw = 1.f - fw;
  for (int u = t; u < 384; u += 256){
    int c = u / 6, s4 = (u % 6) << 2;
    const float* gc = gb + (size_t)c*SG;
    float4 vaa = *(const float4*)(gc + ha*576 + wa*24 + s4);
    float4 vba = *(const float4*)(gc + hb*576 + wa*24 + s4);
    float4 vab = *(const float4*)(gc + ha*576 + wb*24 + s4);
    float4 vbb = *(const float4*)(gc + hb*576 + wb*24 + s4);
    M[(s4+0)*68 + c] = omw*(omh*vaa.x + fh*vba.x) + fw*(omh*vab.x + fh*vbb.x);
    M[(s4+1)*68 + c] = omw*(omh*vaa.y + fh*vba.y) + fw*(omh*vab.y + fh*vbb.y);
    M[(s4+2)*68 + c] = omw*(omh*vaa.z + fh*vba.z) + fw*(omh*vab.z + fh*vbb.z);
    M[(s4+3)*68 + c] = omw*(omh*vaa.w + fh*vba.w) + fw*(omh*vab.w + fh*vbb.w);
  }
}

// per-site channel-mix: acc[i][l-quad] = sum_cc W1[c0+i][cc]*x[cc][l0..l0+3] + b1
// Wl is W1 transposed [cc][o] at stride 68 (conflict-free float4 reads).
__device__ __forceinline__ void site_conv(const float* __restrict__ xs,
    const float* __restrict__ Wl, const float* __restrict__ b1,
    int c0, int l0, float4 acc[4]){
  acc[0] = make_float4(0.f,0.f,0.f,0.f);
  acc[1] = make_float4(0.f,0.f,0.f,0.f);
  acc[2] = make_float4(0.f,0.f,0.f,0.f);
  acc[3] = make_float4(0.f,0.f,0.f,0.f);
  #pragma unroll 8
  for (int cc = 0; cc < 64; ++cc){
    float4 wv = *(const float4*)&Wl[cc*68 + c0];
    float4 xv = *(const float4*)&xs[cc*52 + l0];
    acc[0].x += wv.x*xv.x; acc[0].y += wv.x*xv.y; acc[0].z += wv.x*xv.z; acc[0].w += wv.x*xv.w;
    acc[1].x += wv.y*xv.x; acc[1].y += wv.y*xv.y; acc[1].z += wv.y*xv.z; acc[1].w += wv.y*xv.w;
    acc[2].x += wv.z*xv.x; acc[2].y += wv.z*xv.y; acc[2].z += wv.z*xv.z; acc[2].w += wv.z*xv.w;
    acc[3].x += wv.w*xv.x; acc[3].y += wv.w*xv.y; acc[3].z += wv.w*xv.z; acc[3].w += wv.w*xv.w;
  }
  float b0 = b1[c0+0], bb = b1[c0+1], b2 = b1[c0+2], b3 = b1[c0+3];
  acc[0].x += b0; acc[0].y += b0; acc[0].z += b0; acc[0].w += b0;
  acc[1].x += bb; acc[1].y += bb; acc[1].z += bb; acc[1].w += bb;
  acc[2].x += b2; acc[2].y += b2; acc[2].z += b2; acc[2].w += b2;
  acc[3].x += b3; acc[3].y += b3; acc[3].z += b3; acc[3].w += b3;
}

// one block per (b,h,w) site: fused conv1 (writes txw from registers) +
// partials + msite/gsite stores. txt written back at the proven stride-52
// layout; W1 LDS region aliased by G/red/CM/SX/sxg after the conv.
// LDS 37248 B -> 4 blocks/CU.
__global__ __launch_bounds__(256) void reduce_k(const float* __restrict__ x,
    const float* __restrict__ W1, const float* __restrict__ b1,
    const float* __restrict__ tgh, float* __restrict__ txw,
    float* __restrict__ msite, float* __restrict__ gsite,
    float* __restrict__ part_row, float* __restrict__ pm1,
    float* __restrict__ pm2, float* __restrict__ ps2){
  __shared__ __align__(16) float sh[9312];
  float* txt = sh;            // [64][52]: raw x on load, theta_x after conv
  float* Wl  = sh + 3328;     // [64][68] W1^T; dead after conv, aliased by:
  float* G   = sh + 3328;     //   [24][68]
  float* red = sh + 4960;     //   [512]
  float* CM  = sh + 5472;     //   [24]
  float* SX  = sh + 5496;     //   [48]
  float* sxg = sh + 5544;     //   [48]
  float* M   = sh + 7680;     // [24][68]
  int t = threadIdx.x;
  int bIdx = blockIdx.x;
  int b = bIdx / HWc, hw = bIdx % HWc;
  int h = hw / Ww, w = hw % Ww;
  int ha, hb; float fh; interp1(h, ha, hb, fh);
  int wa, wb; float fw; interp1(w, wa, wb, fw);
  const float* xb = x + ((size_t)b*Cc*HWc + hw)*Ll;
  #pragma unroll
  for (int k = 0; k < 3; ++k){
    int q = t + (k << 8);
    int c = q / 12, v = (q % 12) << 2;
    *(float4*)&txt[c*52+v] = *(const float4*)(xb + (size_t)c*HWL + v);
  }
  // stage W1^T: Wl[i][j] = W1[j][i]; LDS writes contiguous (conflict-free),
  // strided global reads of the 16 KB weight are L1/L2-resident.
  for (int q = t; q < 4096; q += 256){
    int i = q >> 6, j = q & 63;
    Wl[i*68 + j] = W1[j*64 + i];
  }
  gather_m(tgh + (size_t)b*Cc*SG, M, t, ha, hb, wa, wb, fh, fw);
  __syncthreads();
  // conv1 into registers (192 threads: 4c x 4l each); CM in regs meanwhile
  int c0 = (t & 15) << 2, l0q = (t >> 4) << 2;
  float4 acc[4];
  float cmv = 0.f;
  if (t < 192){
    site_conv(txt, Wl, b1, c0, l0q, acc);
  } else if (t < 216){
    int k = t - 192;
    #pragma unroll 8
    for (int c = 0; c < 64; ++c) cmv += M[k*68 + c];
  }
  __syncthreads();   // all xs/Wl reads retired
  if (t < 192){
    *(float4*)&txt[(c0+0)*52 + l0q] = acc[0];
    *(float4*)&txt[(c0+1)*52 + l0q] = acc[1];
    *(float4*)&txt[(c0+2)*52 + l0q] = acc[2];
    *(float4*)&txt[(c0+3)*52 + l0q] = acc[3];
    float* tb = txw + ((size_t)b*Cc*HWc + hw)*Ll;
    *(float4*)(tb + (size_t)(c0+0)*HWL + l0q) = acc[0];
    *(float4*)(tb + (size_t)(c0+1)*HWL + l0q) = acc[1];
    *(float4*)(tb + (size_t)(c0+2)*HWL + l0q) = acc[2];
    *(float4*)(tb + (size_t)(c0+3)*HWL + l0q) = acc[3];
  } else if (t < 216){
    CM[t-192] = cmv;
  }
  __syncthreads();   // txt = theta_x ready; Wl region reusable
  g_fold(txt, G, t);
  if (t >= 192 && t < 240){
    int l = t - 192;
    float s = 0.f;
    #pragma unroll 8
    for (int c = 0; c < 64; ++c) s += txt[c*52 + l];
    SX[l] = s;
  }
  __syncthreads();
  // elementwise product min; l-partition rotated by c (bank spread), int taps
  int c = t & 63, lg = t >> 6;
  float pmin = 3.4e38f;
  const float* Trow = &txt[c*52];
  #pragma unroll
  for (int li = 0; li < 12; ++li){
    int l0r = lg*12 + li + c;
    int l = l0r >= 96 ? l0r - 96 : (l0r >= 48 ? l0r - 48 : l0r);
    int la, lb; float fl; ltaps(l, la, lb, fl);
    float tgv = (1.f-fl)*M[la*68 + c] + fl*M[lb*68 + c];
    pmin = fminf(pmin, Trow[l]*tgv);
  }
  if (t < 48){
    int la, lb; float fl; ltaps(t, la, lb, fl);
    sxg[t] = SX[t] * ((1.f-fl)*CM[la] + fl*CM[lb]);
  }
  // store M and G site-major for final_k
  float* msb = msite + (size_t)bIdx*1536;
  float* gsb = gsite + (size_t)bIdx*1536;
  for (int u = t; u < 384; u += 256){
    int k = u >> 4, c4 = (u & 15) << 2;
    float4 mv;
    mv.x = M[k*68+c4+0]; mv.y = M[k*68+c4+1];
    mv.z = M[k*68+c4+2]; mv.w = M[k*68+c4+3];
    *(float4*)(msb + (u << 2)) = mv;
    float4 gv;
    gv.x = G[k*68+c4+0]; gv.y = G[k*68+c4+1];
    gv.z = G[k*68+c4+2]; gv.w = G[k*68+c4+3];
    *(float4*)(gsb + (u << 2)) = gv;
  }
  // At[i][j] = sum_k G[k][i]*M[k][j]; amin + diag (=rowsum partial)
  int i0 = (t & 15) << 2, j0 = (t >> 4) << 2;
  float a00=0,a01=0,a02=0,a03=0,a10=0,a11=0,a12=0,a13=0;
  float a20=0,a21=0,a22=0,a23=0,a30=0,a31=0,a32=0,a33=0;
  #pragma unroll 4
  for (int k = 0; k < 24; ++k){
    float4 gv = *(const float4*)&G[k*68 + i0];
    float4 mv = *(const float4*)&M[k*68 + j0];
    a00 += gv.x*mv.x; a01 += gv.x*mv.y; a02 += gv.x*mv.z; a03 += gv.x*mv.w;
    a10 += gv.y*mv.x; a11 += gv.y*mv.y; a12 += gv.y*mv.z; a13 += gv.y*mv.w;
    a20 += gv.z*mv.x; a21 += gv.z*mv.y; a22 += gv.z*mv.z; a23 += gv.z*mv.w;
    a30 += gv.w*mv.x; a31 += gv.w*mv.y; a32 += gv.w*mv.z; a33 += gv.w*mv.w;
  }
  float amin = fminf(fminf(fminf(a00,a01),fminf(a02,a03)),
               fminf(fminf(fminf(a10,a11),fminf(a12,a13)),
               fminf(fminf(fminf(a20,a21),fminf(a22,a23)),
                     fminf(fminf(a30,a31),fminf(a32,a33)))));
  if ((t & 15) == (t >> 4)){
    float* pr = part_row + (size_t)bIdx*64 + i0;
    pr[0] = a00; pr[1] = a11; pr[2] = a22; pr[3] = a33;
  }
  red[t] = pmin; red[256+t] = amin;
  __syncthreads();
  if (t < 128){
    red[t] = fminf(red[t], red[t+128]);
    red[256+t] = fminf(red[256+t], red[384+t]);
  }
  __syncthreads();
  if (t < 64){
    float v1 = fminf(red[t], red[t+64]);
    float v2 = fminf(red[256+t], red[320+t]);
    #pragma unroll
    for (int off = 32; off; off >>= 1){
      v1 = fminf(v1, __shfl_down(v1, off));
      v2 = fminf(v2, __shfl_down(v2, off));
    }
    if (t == 0){
      pm1[bIdx] = v1; pm2[bIdx] = v2;
      float tot = 0.f;
      #pragma unroll
      for (int l = 0; l < 48; ++l) tot += sxg[l];
      ps2[bIdx] = tot;
    }
  }
}

// parallel second-stage reduction: 130 blocks (unchanged)
__global__ __launch_bounds__(256) void reduce2_k(const float* __restrict__ part_row,
    const float* __restrict__ pm1, const float* __restrict__ pm2,
    const float* __restrict__ ps2, float* __restrict__ rowsum,
    float* __restrict__ gmin, float* __restrict__ s2v){
  __shared__ float red[512];
  int t = threadIdx.x, blk = blockIdx.x;
  if (blk < 128){
    int b = blk >> 6, c = blk & 63;
    const float* src = part_row + (size_t)b*HWc*64 + c;
    float s = 0.f;
    #pragma unroll
    for (int k = 0; k < 9; ++k){
      int i = t + (k << 8);
      s += src[(size_t)i*64];
    }
    red[t] = s; __syncthreads();
    for (int sgap = 128; sgap >= 64; sgap >>= 1){
      if (t < sgap) red[t] += red[t+sgap];
      __syncthreads();
    }
    if (t < 64){
      float v = red[t];
      #pragma unroll
      for (int off = 32; off; off >>= 1) v += __shfl_down(v, off);
      if (t == 0) rowsum[blk] = v;
    }
  } else if (blk == 128){
    float m1 = 3.4e38f, m2 = 3.4e38f;
    for (int i = t; i < NBLK; i += 256){ m1 = fminf(m1, pm1[i]); m2 = fminf(m2, pm2[i]); }
    red[t] = m1; red[256+t] = m2; __syncthreads();
    for (int s = 128; s >= 1; s >>= 1){
      if (t < s){ red[t] = fminf(red[t], red[t+s]); red[256+t] = fminf(red[256+t], red[256+t+s]); }
      __syncthreads();
    }
    if (t == 0){ gmin[0] = red[0]; gmin[1] = red[256]; }
  } else {
    float sa = 0.f, sb = 0.f;
    for (int i = t; i < HWc; i += 256){ sa += ps2[i]; sb += ps2[HWc + i]; }
    red[t] = sa; red[256+t] = sb; __syncthreads();
    for (int s = 128; s >= 1; s >>= 1){
      if (t < s){ red[t] += red[t+s]; red[256+t] += red[256+t+s]; }
      __syncthreads();
    }
    if (t == 0){ s2v[0] = red[0]; s2v[1] = red[256]; }
  }
}

// one block per (b,h,w): p (tx streamed from global) and d (via P = G·x,
// never forming At). LDS 31808 B -> 5 blocks/CU.  (round-7 form, unchanged)
__global__ __launch_bounds__(256) void final_k(const float* __restrict__ x,
    const float* __restrict__ tx, const float* __restrict__ msite,
    const float* __restrict__ gsite, const float* __restrict__ gmin,
    const float* __restrict__ rowsum, const float* __restrict__ s2v,
    float* __restrict__ outp, float* __restrict__ outd){
  __shared__ __align__(16) float sh[7952];
  float* xs  = sh;            // [64][52] 3328
  float* M   = sh + 3328;     // [24][68] 1632
  float* G   = sh + 4960;     // [24][68] 1632
  float* P   = sh + 6592;     // [24][52] 1248
  float* iv1 = sh + 7840;     // [64]
  float* Xs  = sh + 7904;     // [48]
  int t = threadIdx.x;
  int bIdx = blockIdx.x;
  int b = bIdx / HWc, hw = bIdx % HWc;
  size_t sbase = ((size_t)b*Cc*HWc + hw)*Ll;
  const float* xb  = x  + sbase;
  const float* txb = tx + sbase;
  float m1 = gmin[0], m2 = gmin[1];
  #pragma unroll
  for (int k = 0; k < 3; ++k){
    int q = t + (k << 8);
    int c = q / 12, v = (q % 12) << 2;
    *(float4*)&xs[c*52+v] = *(const float4*)(xb + (size_t)c*HWL + v);
  }
  const float* msb = msite + (size_t)bIdx*1536;
  const float* gsb = gsite + (size_t)bIdx*1536;
  for (int u = t; u < 384; u += 256){
    int k = u >> 4, c4 = (u & 15) << 2;
    *(float4*)&M[k*68 + c4] = *(const float4*)(msb + (u << 2));
    *(float4*)&G[k*68 + c4] = *(const float4*)(gsb + (u << 2));
  }
  if (t < 64) iv1[t] = 1.f/(rowsum[b*64 + t] - m1*CNT1f);
  float invd2 = 1.f/(s2v[b] - m2*CNT2f);
  __syncthreads();
  // P[k][l] = sum_c G[k][c]*x[c][l]  (192 thr: 1k x 6l each)
  if (t < 192){
    int k0 = t >> 3, l0 = (t & 7)*6;
    float c0=0,c1=0,c2=0,c3=0,c4=0,c5=0;
    const float* Gr = &G[k0*68];
    #pragma unroll 8
    for (int i = 0; i < 64; ++i){
      float gv = Gr[i];
      const float* xr = &xs[i*52 + l0];
      c0 += gv*xr[0]; c1 += gv*xr[1]; c2 += gv*xr[2];
      c3 += gv*xr[3]; c4 += gv*xr[4]; c5 += gv*xr[5];
    }
    float* pr = &P[k0*52 + l0];
    pr[0]=c0; pr[1]=c1; pr[2]=c2; pr[3]=c3; pr[4]=c4; pr[5]=c5;
  } else if (t < 240){
    int l = t - 192;
    float s = 0.f;
    #pragma unroll 8
    for (int c = 0; c < 64; ++c) s += xs[c*52 + l];
    Xs[l] = s;
  }
  // p = (tx*tg - m1)*iv1[c]*x — tx streamed, tg expanded via shared taps
  __syncthreads();
  #pragma unroll
  for (int k = 0; k < 3; ++k){
    int q = t + (k << 8);
    int c = q / 12, l4 = (q % 12) << 2;
    int hh = l4 >> 1;
    int im1 = hh - 1 < 0 ? 0 : hh - 1;
    int ip2 = hh + 2 > 23 ? 23 : hh + 2;
    float Mm1 = M[im1*68 + c];
    float M0  = M[hh*68 + c];
    float M1  = M[(hh+1)*68 + c];
    float M2  = M[ip2*68 + c];
    float4 a  = *(const float4*)(txb + (size_t)c*HWL + l4);
    float4 xv = *(const float4*)&xs[c*52 + l4];
    float s = iv1[c];
    float4 r;
    r.x = (a.x*(0.25f*Mm1 + 0.75f*M0) - m1)*s*xv.x;
    r.y = (a.y*(0.75f*M0  + 0.25f*M1) - m1)*s*xv.y;
    r.z = (a.z*(0.25f*M0  + 0.75f*M1) - m1)*s*xv.z;
    r.w = (a.w*(0.75f*M1  + 0.25f*M2) - m1)*s*xv.w;
    *(float4*)(outp + sbase + (size_t)c*HWL + l4) = r;
  }
  __syncthreads();   // P/Xs ready
  // d[j][l] = invd2*(sum_k M[k][j]*P[k][l] - m2*Xs[l]); 256 thr: 4j x 3l
  {
    int j0 = (t >> 4) << 2, l0 = (t & 15)*3;
    float d00=0,d01=0,d02=0,d10=0,d11=0,d12=0;
    float d20=0,d21=0,d22=0,d30=0,d31=0,d32=0;
    #pragma unroll 4
    for (int k = 0; k < 24; ++k){
      float4 mv = *(const float4*)&M[k*68 + j0];
      const float* pr = &P[k*52 + l0];
      float p0 = pr[0], p1 = pr[1], p2 = pr[2];
      d00 += mv.x*p0; d01 += mv.x*p1; d02 += mv.x*p2;
      d10 += mv.y*p0; d11 += mv.y*p1; d12 += mv.y*p2;
      d20 += mv.z*p0; d21 += mv.z*p1; d22 += mv.z*p2;
      d30 += mv.w*p0; d31 += mv.w*p1; d32 += mv.w*p2;
    }
    float x0 = m2*Xs[l0+0], x1 = m2*Xs[l0+1], x2 = m2*Xs[l0+2];
    float* o0 = outd + sbase + (size_t)(j0+0)*HWL + l0;
    float* o1 = outd + sbase + (size_t)(j0+1)*HWL + l0;
    float* o2 = outd + sbase + (size_t)(j0+2)*HWL + l0;
    float* o3 = outd + sbase + (size_t)(j0+3)*HWL + l0;
    o0[0]=(d00-x0)*invd2; o0[1]=(d01-x1)*invd2; o0[2]=(d02-x2)*invd2;
    o1[0]=(d10-x0)*invd2; o1[1]=(d11-x1)*invd2; o1[2]=(d12-x2)*invd2;
    o2[0]=(d20-x0)*invd2; o2[1]=(d21-x1)*invd2; o2[2]=(d22-x2)*invd2;
    o3[0]=(d30-x0)*invd2; o3[1]=(d31-x1)*invd2; o3[2]=(d32-x2)*invd2;
  }
}

extern "C" void kernel_launch(void* const* d_in, const int* in_sizes, int n_in,
                              void* d_out, int out_size, void* d_ws, size_t ws_size,
                              hipStream_t stream){
  (void)in_sizes; (void)n_in; (void)out_size; (void)ws_size;
  const float* x  = (const float*)d_in[0];
  const float* g  = (const float*)d_in[1];
  const float* W1 = (const float*)d_in[2];
  const float* b1 = (const float*)d_in[3];
  const float* W2 = (const float*)d_in[4];
  const float* b2 = (const float*)d_in[5];
  float* outp = (float*)d_out;
  float* outd = outp + (size_t)Bb*Cc*HWL;
  float* ws   = (float*)d_ws;
  float* txw    = ws;                               // 14,155,776 floats
  float* tghw   = txw + (size_t)Bb*Cc*HWL;          // 1,769,472
  float* msite  = tghw + (size_t)Bb*Cc*SG;          // NBLK*1536
  float* gsite  = msite + (size_t)NBLK*1536;        // NBLK*1536
  float* part_row = gsite + (size_t)NBLK*1536;      // NBLK*64
  float* pm1 = part_row + (size_t)NBLK*64;          // NBLK
  float* pm2 = pm1 + NBLK;                          // NBLK
  float* ps2 = pm2 + NBLK;                          // NBLK
  float* rowsum = ps2 + NBLK;                       // 128
  float* gmin = rowsum + 128;                       // 2
  float* s2v  = gmin + 2;                           // 2

  hipLaunchKernelGGL(conv_k, dim3(Bb*(SG/64)), dim3(256), 0, stream, g, W2, b2, tghw, SG);
  hipLaunchKernelGGL(reduce_k, dim3(NBLK), dim3(256), 0, stream, x, W1, b1, tghw, txw,
                     msite, gsite, part_row, pm1, pm2, ps2);
  hipLaunchKernelGGL(reduce2_k, dim3(130), dim3(256), 0, stream, part_row, pm1, pm2, ps2,
                     rowsum, gmin, s2v);
  hipLaunchKernelGGL(final_k, dim3(NBLK), dim3(256), 0, stream, x, txw, msite, gsite,
                     gmin, rowsum, s2v, outp, outd);
}

// Round 10
// 308.537 us; speedup vs baseline: 1.0405x; 1.0325x over previous
//
#include <hip/hip_runtime.h>

#define Bb 2
#define Cc 64
#define Hh 48
#define Ww 48
#define Ll 48
#define HWc (Hh*Ww)          /* 2304 */
#define HWL (HWc*Ll)         /* 110592 */
#define GHh 24
#define SG (GHh*GHh*GHh)     /* 13824 */
#define NBLK (Bb*HWc)        /* 4608 */
#define CNT1f 110592.0f
#define CNT2f 9437184.0f     /* HW*C*C */

// half-pixel trilinear taps for 24 -> 48 (matches jax.image.resize 'trilinear')
__device__ __forceinline__ void interp1(int i, int& a, int& b, float& f){
  float src = i*0.5f - 0.25f;
  float fl = floorf(src);
  f = src - fl;
  int i0 = (int)fl;
  a = i0 < 0 ? 0 : i0;
  int i1 = i0 + 1;
  b = i1 > (GHh-1) ? (GHh-1) : i1;
}

// integer form of the l-taps (bit-identical: fl is exactly 0.25/0.75)
__device__ __forceinline__ void ltaps(int l, int& a, int& b, float& f){
  int i0 = (l - 1) >> 1;             // arithmetic shift; l=0 -> -1
  a = i0 < 0 ? 0 : i0;
  b = i0 + 1 > 23 ? 23 : i0 + 1;
  f = (l & 1) ? 0.25f : 0.75f;
}

// out[b,o,s] = sum_c W[o,c]*in[b,c,s] + bias[o] — used only for theta_g (half-res)
__global__ __launch_bounds__(256) void conv_k(const float* __restrict__ in,
    const float* __restrict__ Wm, const float* __restrict__ bias,
    float* __restrict__ out, int S){
  __shared__ __align__(16) float Wl[64][68];   // Wl[c][o]
  __shared__ __align__(16) float xl[64][68];   // xl[c][s]
  int t = threadIdx.x;
  int ntile = S >> 6;
  int b  = blockIdx.x / ntile;
  int s0 = (blockIdx.x % ntile) << 6;
  for (int q = t; q < 4096; q += 256){
    int o = q >> 6, c = q & 63;
    Wl[c][o] = Wm[q];
  }
  const float* inb = in + (size_t)b*Cc*S + s0;
  for (int q = t; q < 1024; q += 256){
    int c = q >> 4, v = (q & 15) << 2;
    float4 val = *(const float4*)(inb + (size_t)c*S + v);
    *(float4*)&xl[c][v] = val;
  }
  __syncthreads();
  int o0 = (t & 15) << 2, s1 = (t >> 4) << 2;
  float a00=0,a01=0,a02=0,a03=0,a10=0,a11=0,a12=0,a13=0;
  float a20=0,a21=0,a22=0,a23=0,a30=0,a31=0,a32=0,a33=0;
  #pragma unroll 8
  for (int c = 0; c < 64; ++c){
    float4 wv = *(const float4*)&Wl[c][o0];
    float4 xv = *(const float4*)&xl[c][s1];
    a00 += wv.x*xv.x; a01 += wv.x*xv.y; a02 += wv.x*xv.z; a03 += wv.x*xv.w;
    a10 += wv.y*xv.x; a11 += wv.y*xv.y; a12 += wv.y*xv.z; a13 += wv.y*xv.w;
    a20 += wv.z*xv.x; a21 += wv.z*xv.y; a22 += wv.z*xv.z; a23 += wv.z*xv.w;
    a30 += wv.w*xv.x; a31 += wv.w*xv.y; a32 += wv.w*xv.z; a33 += wv.w*xv.w;
  }
  float* ob = out + (size_t)b*Cc*S + s0 + s1;
  float b0 = bias[o0+0], b1v = bias[o0+1], b2v = bias[o0+2], b3 = bias[o0+3];
  { float4 r = make_float4(a00+b0,a01+b0,a02+b0,a03+b0); *(float4*)(ob + (size_t)(o0+0)*S) = r; }
  { float4 r = make_float4(a10+b1v,a11+b1v,a12+b1v,a13+b1v); *(float4*)(ob + (size_t)(o0+1)*S) = r; }
  { float4 r = make_float4(a20+b2v,a21+b2v,a22+b2v,a23+b2v); *(float4*)(ob + (size_t)(o0+2)*S) = r; }
  { float4 r = make_float4(a30+b3,a31+b3,a32+b3,a33+b3); *(float4*)(ob + (size_t)(o0+3)*S) = r; }
}

// G-fold: G[k][c] = sum_l w(l,k)*txt[c][l] (txt stride 52)
__device__ __forceinline__ void g_fold(const float* __restrict__ txt,
    float* __restrict__ G, int t){
  int c = t >> 2, kb = (t & 3)*6;
  const float* T = &txt[c*52];
  #pragma unroll
  for (int i = 0; i < 6; ++i){
    int k = kb + i;
    float v;
    if (k == 0)       v = T[0] + 0.75f*T[1] + 0.25f*T[2];
    else if (k == 23) v = 0.25f*T[45] + 0.75f*T[46] + T[47];
    else              v = 0.25f*T[2*k-1] + 0.75f*T[2*k]
                        + 0.75f*T[2*k+1] + 0.25f*T[2*k+2];
    G[k*68 + c] = v;
  }
}

// M[k][c] = bilinear(h,w) of half-res tgh (h-lerp then w-lerp).
__device__ __forceinline__ void gather_m(const float* __restrict__ gb,
    float* __restrict__ M, int t, int ha, int hb, int wa, int wb,
    float fh, float fw){
  float omh = 1.f - fh, omw = 1.f - fw;
  for (int u = t; u < 384; u += 256){
    int c = u / 6, s4 = (u % 6) << 2;
    const float* gc = gb + (size_t)c*SG;
    float4 vaa = *(const float4*)(gc + ha*576 + wa*24 + s4);
    float4 vba = *(const float4*)(gc + hb*576 + wa*24 + s4);
    float4 vab = *(const float4*)(gc + ha*576 + wb*24 + s4);
    float4 vbb = *(const float4*)(gc + hb*576 + wb*24 + s4);
    M[(s4+0)*68 + c] = omw*(omh*vaa.x + fh*vba.x) + fw*(omh*vab.x + fh*vbb.x);
    M[(s4+1)*68 + c] = omw*(omh*vaa.y + fh*vba.y) + fw*(omh*vab.y + fh*vbb.y);
    M[(s4+2)*68 + c] = omw*(omh*vaa.z + fh*vba.z) + fw*(omh*vab.z + fh*vbb.z);
    M[(s4+3)*68 + c] = omw*(omh*vaa.w + fh*vba.w) + fw*(omh*vab.w + fh*vbb.w);
  }
}

// per-site channel-mix: acc[i][l-quad] = sum_cc W1[c0+i][cc]*x[cc][l0..l0+3] + b1
// Wl is W1 transposed [cc][o] at stride 68.
__device__ __forceinline__ void site_conv(const float* __restrict__ xs,
    const float* __restrict__ Wl, const float* __restrict__ b1,
    int c0, int l0, float4 acc[4]){
  acc[0] = make_float4(0.f,0.f,0.f,0.f);
  acc[1] = make_float4(0.f,0.f,0.f,0.f);
  acc[2] = make_float4(0.f,0.f,0.f,0.f);
  acc[3] = make_float4(0.f,0.f,0.f,0.f);
  #pragma unroll 8
  for (int cc = 0; cc < 64; ++cc){
    float4 wv = *(const float4*)&Wl[cc*68 + c0];
    float4 xv = *(const float4*)&xs[cc*52 + l0];
    acc[0].x += wv.x*xv.x; acc[0].y += wv.x*xv.y; acc[0].z += wv.x*xv.z; acc[0].w += wv.x*xv.w;
    acc[1].x += wv.y*xv.x; acc[1].y += wv.y*xv.y; acc[1].z += wv.y*xv.z; acc[1].w += wv.y*xv.w;
    acc[2].x += wv.z*xv.x; acc[2].y += wv.z*xv.y; acc[2].z += wv.z*xv.z; acc[2].w += wv.z*xv.w;
    acc[3].x += wv.w*xv.x; acc[3].y += wv.w*xv.y; acc[3].z += wv.w*xv.z; acc[3].w += wv.w*xv.w;
  }
  float b0 = b1[c0+0], bb = b1[c0+1], b2 = b1[c0+2], b3 = b1[c0+3];
  acc[0].x += b0; acc[0].y += b0; acc[0].z += b0; acc[0].w += b0;
  acc[1].x += bb; acc[1].y += bb; acc[1].z += bb; acc[1].w += bb;
  acc[2].x += b2; acc[2].y += b2; acc[2].z += b2; acc[2].w += b2;
  acc[3].x += b3; acc[3].y += b3; acc[3].z += b3; acc[3].w += b3;
}

// one block per (b,h,w) site: fused conv1 + partials + txw/msite/gsite stores.
// vs round 8 (correct baseline): (a) W1^T staged with COALESCED global reads;
// (b) txw stored AFTER the txt barrier with the coalesced row pattern
// (round 8 scattered 16B quads across 16 rows per thread).
// Conv tile mapping is round 8's (16 c-quads x 12 l-quads) — known correct.
__global__ __launch_bounds__(256) void reduce_k(const float* __restrict__ x,
    const float* __restrict__ W1, const float* __restrict__ b1,
    const float* __restrict__ tgh, float* __restrict__ txw,
    float* __restrict__ msite, float* __restrict__ gsite,
    float* __restrict__ part_row, float* __restrict__ pm1,
    float* __restrict__ pm2, float* __restrict__ ps2){
  __shared__ __align__(16) float sh[9312];
  float* txt = sh;            // [64][52]: raw x on load, theta_x after conv
  float* Wl  = sh + 3328;     // [64][68] W1^T; dead after conv, aliased by:
  float* G   = sh + 3328;     //   [24][68]
  float* red = sh + 4960;     //   [512]
  float* CM  = sh + 5472;     //   [24]
  float* SX  = sh + 5496;     //   [48]
  float* sxg = sh + 5544;     //   [48]
  float* M   = sh + 7680;     // [24][68]
  int t = threadIdx.x;
  int bIdx = blockIdx.x;
  int b = bIdx / HWc, hw = bIdx % HWc;
  int h = hw / Ww, w = hw % Ww;
  int ha, hb; float fh; interp1(h, ha, hb, fh);
  int wa, wb; float fw; interp1(w, wa, wb, fw);
  const float* xb = x + ((size_t)b*Cc*HWc + hw)*Ll;
  #pragma unroll
  for (int k = 0; k < 3; ++k){
    int q = t + (k << 8);
    int c = q / 12, v = (q % 12) << 2;
    *(float4*)&txt[c*52+v] = *(const float4*)(xb + (size_t)c*HWL + v);
  }
  // stage W1^T: Wl[c][o] = W1[o][c]; global read contiguous (coalesced),
  // LDS write 8-way-conflicted but only 16 wave-instructions (negligible).
  for (int q = t; q < 4096; q += 256){
    Wl[(q & 63)*68 + (q >> 6)] = W1[q];
  }
  gather_m(tgh + (size_t)b*Cc*SG, M, t, ha, hb, wa, wb, fh, fw);
  __syncthreads();
  // conv1 into registers (192 threads: 4c x 4l each); CM in regs meanwhile
  int c0 = (t & 15) << 2, l0q = (t >> 4) << 2;
  float4 acc[4];
  float cmv = 0.f;
  if (t < 192){
    site_conv(txt, Wl, b1, c0, l0q, acc);
  } else if (t < 216){
    int k = t - 192;
    #pragma unroll 8
    for (int c = 0; c < 64; ++c) cmv += M[k*68 + c];
  }
  __syncthreads();   // all xs/Wl reads retired
  if (t < 192){
    *(float4*)&txt[(c0+0)*52 + l0q] = acc[0];
    *(float4*)&txt[(c0+1)*52 + l0q] = acc[1];
    *(float4*)&txt[(c0+2)*52 + l0q] = acc[2];
    *(float4*)&txt[(c0+3)*52 + l0q] = acc[3];
  } else if (t < 216){
    CM[t-192] = cmv;
  }
  __syncthreads();   // txt = theta_x ready; Wl region reusable
  // coalesced txw store (contiguous 192B rows), from LDS
  {
    float* tb = txw + ((size_t)b*Cc*HWc + hw)*Ll;
    #pragma unroll
    for (int k = 0; k < 3; ++k){
      int q = t + (k << 8);
      int c = q / 12, v = (q % 12) << 2;
      *(float4*)(tb + (size_t)c*HWL + v) = *(const float4*)&txt[c*52+v];
    }
  }
  g_fold(txt, G, t);
  if (t >= 192 && t < 240){
    int l = t - 192;
    float s = 0.f;
    #pragma unroll 8
    for (int c = 0; c < 64; ++c) s += txt[c*52 + l];
    SX[l] = s;
  }
  __syncthreads();
  // elementwise product min; l-partition rotated by c (bank spread), int taps
  int c = t & 63, lg = t >> 6;
  float pmin = 3.4e38f;
  const float* Trow = &txt[c*52];
  #pragma unroll
  for (int li = 0; li < 12; ++li){
    int l0r = lg*12 + li + c;
    int l = l0r >= 96 ? l0r - 96 : (l0r >= 48 ? l0r - 48 : l0r);
    int la, lb; float fl; ltaps(l, la, lb, fl);
    float tgv = (1.f-fl)*M[la*68 + c] + fl*M[lb*68 + c];
    pmin = fminf(pmin, Trow[l]*tgv);
  }
  if (t < 48){
    int la, lb; float fl; ltaps(t, la, lb, fl);
    sxg[t] = SX[t] * ((1.f-fl)*CM[la] + fl*CM[lb]);
  }
  // store M and G site-major for final_k
  float* msb = msite + (size_t)bIdx*1536;
  float* gsb = gsite + (size_t)bIdx*1536;
  for (int u = t; u < 384; u += 256){
    int k = u >> 4, c4 = (u & 15) << 2;
    float4 mv;
    mv.x = M[k*68+c4+0]; mv.y = M[k*68+c4+1];
    mv.z = M[k*68+c4+2]; mv.w = M[k*68+c4+3];
    *(float4*)(msb + (u << 2)) = mv;
    float4 gv;
    gv.x = G[k*68+c4+0]; gv.y = G[k*68+c4+1];
    gv.z = G[k*68+c4+2]; gv.w = G[k*68+c4+3];
    *(float4*)(gsb + (u << 2)) = gv;
  }
  // At[i][j] = sum_k G[k][i]*M[k][j]; amin + diag (=rowsum partial)
  int i0 = (t & 15) << 2, j0 = (t >> 4) << 2;
  float a00=0,a01=0,a02=0,a03=0,a10=0,a11=0,a12=0,a13=0;
  float a20=0,a21=0,a22=0,a23=0,a30=0,a31=0,a32=0,a33=0;
  #pragma unroll 4
  for (int k = 0; k < 24; ++k){
    float4 gv = *(const float4*)&G[k*68 + i0];
    float4 mv = *(const float4*)&M[k*68 + j0];
    a00 += gv.x*mv.x; a01 += gv.x*mv.y; a02 += gv.x*mv.z; a03 += gv.x*mv.w;
    a10 += gv.y*mv.x; a11 += gv.y*mv.y; a12 += gv.y*mv.z; a13 += gv.y*mv.w;
    a20 += gv.z*mv.x; a21 += gv.z*mv.y; a22 += gv.z*mv.z; a23 += gv.z*mv.w;
    a30 += gv.w*mv.x; a31 += gv.w*mv.y; a32 += gv.w*mv.z; a33 += gv.w*mv.w;
  }
  float amin = fminf(fminf(fminf(a00,a01),fminf(a02,a03)),
               fminf(fminf(fminf(a10,a11),fminf(a12,a13)),
               fminf(fminf(fminf(a20,a21),fminf(a22,a23)),
                     fminf(fminf(a30,a31),fminf(a32,a33)))));
  if ((t & 15) == (t >> 4)){
    float* pr = part_row + (size_t)bIdx*64 + i0;
    pr[0] = a00; pr[1] = a11; pr[2] = a22; pr[3] = a33;
  }
  red[t] = pmin; red[256+t] = amin;
  __syncthreads();
  if (t < 128){
    red[t] = fminf(red[t], red[t+128]);
    red[256+t] = fminf(red[256+t], red[384+t]);
  }
  __syncthreads();
  if (t < 64){
    float v1 = fminf(red[t], red[t+64]);
    float v2 = fminf(red[256+t], red[320+t]);
    #pragma unroll
    for (int off = 32; off; off >>= 1){
      v1 = fminf(v1, __shfl_down(v1, off));
      v2 = fminf(v2, __shfl_down(v2, off));
    }
    if (t == 0){
      pm1[bIdx] = v1; pm2[bIdx] = v2;
      float tot = 0.f;
      #pragma unroll
      for (int l = 0; l < 48; ++l) tot += sxg[l];
      ps2[bIdx] = tot;
    }
  }
}

// parallel second-stage reduction: 130 blocks (unchanged)
__global__ __launch_bounds__(256) void reduce2_k(const float* __restrict__ part_row,
    const float* __restrict__ pm1, const float* __restrict__ pm2,
    const float* __restrict__ ps2, float* __restrict__ rowsum,
    float* __restrict__ gmin, float* __restrict__ s2v){
  __shared__ float red[512];
  int t = threadIdx.x, blk = blockIdx.x;
  if (blk < 128){
    int b = blk >> 6, c = blk & 63;
    const float* src = part_row + (size_t)b*HWc*64 + c;
    float s = 0.f;
    #pragma unroll
    for (int k = 0; k < 9; ++k){
      int i = t + (k << 8);
      s += src[(size_t)i*64];
    }
    red[t] = s; __syncthreads();
    for (int sgap = 128; sgap >= 64; sgap >>= 1){
      if (t < sgap) red[t] += red[t+sgap];
      __syncthreads();
    }
    if (t < 64){
      float v = red[t];
      #pragma unroll
      for (int off = 32; off; off >>= 1) v += __shfl_down(v, off);
      if (t == 0) rowsum[blk] = v;
    }
  } else if (blk == 128){
    float m1 = 3.4e38f, m2 = 3.4e38f;
    for (int i = t; i < NBLK; i += 256){ m1 = fminf(m1, pm1[i]); m2 = fminf(m2, pm2[i]); }
    red[t] = m1; red[256+t] = m2; __syncthreads();
    for (int s = 128; s >= 1; s >>= 1){
      if (t < s){ red[t] = fminf(red[t], red[t+s]); red[256+t] = fminf(red[256+t], red[256+t+s]); }
      __syncthreads();
    }
    if (t == 0){ gmin[0] = red[0]; gmin[1] = red[256]; }
  } else {
    float sa = 0.f, sb = 0.f;
    for (int i = t; i < HWc; i += 256){ sa += ps2[i]; sb += ps2[HWc + i]; }
    red[t] = sa; red[256+t] = sb; __syncthreads();
    for (int s = 128; s >= 1; s >>= 1){
      if (t < s){ red[t] += red[t+s]; red[256+t] += red[256+t+s]; }
      __syncthreads();
    }
    if (t == 0){ s2v[0] = red[0]; s2v[1] = red[256]; }
  }
}

// one block per (b,h,w): p (tx streamed from global) and d (via P = G·x,
// never forming At). LDS 31808 B -> 5 blocks/CU.
__global__ __launch_bounds__(256) void final_k(const float* __restrict__ x,
    const float* __restrict__ tx, const float* __restrict__ msite,
    const float* __restrict__ gsite, const float* __restrict__ gmin,
    const float* __restrict__ rowsum, const float* __restrict__ s2v,
    float* __restrict__ outp, float* __restrict__ outd){
  __shared__ __align__(16) float sh[7952];
  float* xs  = sh;            // [64][52] 3328
  float* M   = sh + 3328;     // [24][68] 1632
  float* G   = sh + 4960;     // [24][68] 1632
  float* P   = sh + 6592;     // [24][52] 1248
  float* iv1 = sh + 7840;     // [64]
  float* Xs  = sh + 7904;     // [48]
  int t = threadIdx.x;
  int bIdx = blockIdx.x;
  int b = bIdx / HWc, hw = bIdx % HWc;
  size_t sbase = ((size_t)b*Cc*HWc + hw)*Ll;
  const float* xb  = x  + sbase;
  const float* txb = tx + sbase;
  float m1 = gmin[0], m2 = gmin[1];
  #pragma unroll
  for (int k = 0; k < 3; ++k){
    int q = t + (k << 8);
    int c = q / 12, v = (q % 12) << 2;
    *(float4*)&xs[c*52+v] = *(const float4*)(xb + (size_t)c*HWL + v);
  }
  const float* msb = msite + (size_t)bIdx*1536;
  const float* gsb = gsite + (size_t)bIdx*1536;
  for (int u = t; u < 384; u += 256){
    int k = u >> 4, c4 = (u & 15) << 2;
    *(float4*)&M[k*68 + c4] = *(const float4*)(msb + (u << 2));
    *(float4*)&G[k*68 + c4] = *(const float4*)(gsb + (u << 2));
  }
  if (t < 64) iv1[t] = 1.f/(rowsum[b*64 + t] - m1*CNT1f);
  float invd2 = 1.f/(s2v[b] - m2*CNT2f);
  __syncthreads();
  // P[k][l] = sum_c G[k][c]*x[c][l]  (192 thr: 1k x 6l each)
  if (t < 192){
    int k0 = t >> 3, l0 = (t & 7)*6;
    float c0=0,c1=0,c2=0,c3=0,c4=0,c5=0;
    const float* Gr = &G[k0*68];
    #pragma unroll 8
    for (int i = 0; i < 64; ++i){
      float gv = Gr[i];
      const float* xr = &xs[i*52 + l0];
      c0 += gv*xr[0]; c1 += gv*xr[1]; c2 += gv*xr[2];
      c3 += gv*xr[3]; c4 += gv*xr[4]; c5 += gv*xr[5];
    }
    float* pr = &P[k0*52 + l0];
    pr[0]=c0; pr[1]=c1; pr[2]=c2; pr[3]=c3; pr[4]=c4; pr[5]=c5;
  } else if (t < 240){
    int l = t - 192;
    float s = 0.f;
    #pragma unroll 8
    for (int c = 0; c < 64; ++c) s += xs[c*52 + l];
    Xs[l] = s;
  }
  // p = (tx*tg - m1)*iv1[c]*x — tx streamed, tg expanded via shared taps
  __syncthreads();
  #pragma unroll
  for (int k = 0; k < 3; ++k){
    int q = t + (k << 8);
    int c = q / 12, l4 = (q % 12) << 2;
    int hh = l4 >> 1;
    int im1 = hh - 1 < 0 ? 0 : hh - 1;
    int ip2 = hh + 2 > 23 ? 23 : hh + 2;
    float Mm1 = M[im1*68 + c];
    float M0  = M[hh*68 + c];
    float M1  = M[(hh+1)*68 + c];
    float M2  = M[ip2*68 + c];
    float4 a  = *(const float4*)(txb + (size_t)c*HWL + l4);
    float4 xv = *(const float4*)&xs[c*52 + l4];
    float s = iv1[c];
    float4 r;
    r.x = (a.x*(0.25f*Mm1 + 0.75f*M0) - m1)*s*xv.x;
    r.y = (a.y*(0.75f*M0  + 0.25f*M1) - m1)*s*xv.y;
    r.z = (a.z*(0.25f*M0  + 0.75f*M1) - m1)*s*xv.z;
    r.w = (a.w*(0.75f*M1  + 0.25f*M2) - m1)*s*xv.w;
    *(float4*)(outp + sbase + (size_t)c*HWL + l4) = r;
  }
  __syncthreads();   // P/Xs ready
  // d[j][l] = invd2*(sum_k M[k][j]*P[k][l] - m2*Xs[l]); 256 thr: 4j x 3l
  {
    int j0 = (t >> 4) << 2, l0 = (t & 15)*3;
    float d00=0,d01=0,d02=0,d10=0,d11=0,d12=0;
    float d20=0,d21=0,d22=0,d30=0,d31=0,d32=0;
    #pragma unroll 4
    for (int k = 0; k < 24; ++k){
      float4 mv = *(const float4*)&M[k*68 + j0];
      const float* pr = &P[k*52 + l0];
      float p0 = pr[0], p1 = pr[1], p2 = pr[2];
      d00 += mv.x*p0; d01 += mv.x*p1; d02 += mv.x*p2;
      d10 += mv.y*p0; d11 += mv.y*p1; d12 += mv.y*p2;
      d20 += mv.z*p0; d21 += mv.z*p1; d22 += mv.z*p2;
      d30 += mv.w*p0; d31 += mv.w*p1; d32 += mv.w*p2;
    }
    float x0 = m2*Xs[l0+0], x1 = m2*Xs[l0+1], x2 = m2*Xs[l0+2];
    float* o0 = outd + sbase + (size_t)(j0+0)*HWL + l0;
    float* o1 = outd + sbase + (size_t)(j0+1)*HWL + l0;
    float* o2 = outd + sbase + (size_t)(j0+2)*HWL + l0;
    float* o3 = outd + sbase + (size_t)(j0+3)*HWL + l0;
    o0[0]=(d00-x0)*invd2; o0[1]=(d01-x1)*invd2; o0[2]=(d02-x2)*invd2;
    o1[0]=(d10-x0)*invd2; o1[1]=(d11-x1)*invd2; o1[2]=(d12-x2)*invd2;
    o2[0]=(d20-x0)*invd2; o2[1]=(d21-x1)*invd2; o2[2]=(d22-x2)*invd2;
    o3[0]=(d30-x0)*invd2; o3[1]=(d31-x1)*invd2; o3[2]=(d32-x2)*invd2;
  }
}

extern "C" void kernel_launch(void* const* d_in, const int* in_sizes, int n_in,
                              void* d_out, int out_size, void* d_ws, size_t ws_size,
                              hipStream_t stream){
  (void)in_sizes; (void)n_in; (void)out_size; (void)ws_size;
  const float* x  = (const float*)d_in[0];
  const float* g  = (const float*)d_in[1];
  const float* W1 = (const float*)d_in[2];
  const float* b1 = (const float*)d_in[3];
  const float* W2 = (const float*)d_in[4];
  const float* b2 = (const float*)d_in[5];
  float* outp = (float*)d_out;
  float* outd = outp + (size_t)Bb*Cc*HWL;
  float* ws   = (float*)d_ws;
  float* txw    = ws;                               // 14,155,776 floats
  float* tghw   = txw + (size_t)Bb*Cc*HWL;          // 1,769,472
  float* msite  = tghw + (size_t)Bb*Cc*SG;          // NBLK*1536
  float* gsite  = msite + (size_t)NBLK*1536;        // NBLK*1536
  float* part_row = gsite + (size_t)NBLK*1536;      // NBLK*64
  float* pm1 = part_row + (size_t)NBLK*64;          // NBLK
  float* pm2 = pm1 + NBLK;                          // NBLK
  float* ps2 = pm2 + NBLK;                          // NBLK
  float* rowsum = ps2 + NBLK;                       // 128
  float* gmin = rowsum + 128;                       // 2
  float* s2v  = gmin + 2;                           // 2

  hipLaunchKernelGGL(conv_k, dim3(Bb*(SG/64)), dim3(256), 0, stream, g, W2, b2, tghw, SG);
  hipLaunchKernelGGL(reduce_k, dim3(NBLK), dim3(256), 0, stream, x, W1, b1, tghw, txw,
                     msite, gsite, part_row, pm1, pm2, ps2);
  hipLaunchKernelGGL(reduce2_k, dim3(130), dim3(256), 0, stream, part_row, pm1, pm2, ps2,
                     rowsum, gmin, s2v);
  hipLaunchKernelGGL(final_k, dim3(NBLK), dim3(256), 0, stream, x, txw, msite, gsite,
                     gmin, rowsum, s2v, outp, outd);
}